// Round 1
// baseline (245.713 us; speedup 1.0000x reference)
//
#include <hip/hip_runtime.h>
#include <stdint.h>

// CustomMultiHeadAttention: B=2, S=4096, E=512, H=8, Dh=64, fp32 in/out.
// Strategy: bf16 MFMA pipeline (threshold is bf16-scale 5.86e-3).
//   ws layout (needs 34 MB):
//     [0,        8 MB)  xb   : x as bf16 [8192][512]   (reused as attn output)
//     [8 MB,    10 MB)  Wt   : Wq,Wk,Wv,Wo transposed bf16 [4][512 n][512 k]
//     [10 MB,   18 MB)  Qb   : bf16 [8192][512]
//     [18 MB,   26 MB)  Kb   : bf16 [8192][512]
//     [26 MB,   34 MB)  Vtb  : bf16 [b*512 + h*64 + d][4096 s]  (V transposed)

typedef __bf16 bf16_t;
typedef bf16_t bf16x8 __attribute__((ext_vector_type(8)));
typedef float f32x4 __attribute__((ext_vector_type(4)));
typedef unsigned short u16;

__device__ __forceinline__ u16 f2bf(float f) {
  return __builtin_bit_cast(u16, (bf16_t)f);
}

// async global->LDS, 16B per lane; LDS dest must be uniform-base + lane*16
__device__ __forceinline__ void gll16(const void* g, void* l) {
  __builtin_amdgcn_global_load_lds((__attribute__((address_space(1))) void*)(void*)(g),
                                   (__attribute__((address_space(3))) void*)(l), 16, 0, 0);
}

template <int CTRL>
__device__ __forceinline__ float dppf(float x) {
  return __builtin_bit_cast(float,
      __builtin_amdgcn_mov_dpp(__builtin_bit_cast(int, x), CTRL, 0xf, 0xf, false));
}
// reductions across the 16-lane row group (score-fragment col lanes), via row_ror
__device__ __forceinline__ float rmax16(float x) {
  x = fmaxf(x, dppf<0x121>(x)); x = fmaxf(x, dppf<0x122>(x));
  x = fmaxf(x, dppf<0x124>(x)); x = fmaxf(x, dppf<0x128>(x));
  return x;
}
__device__ __forceinline__ float rsum16(float x) {
  x += dppf<0x121>(x); x += dppf<0x122>(x);
  x += dppf<0x124>(x); x += dppf<0x128>(x);
  return x;
}

// ---------------- prep: fp32 -> bf16 convert ----------------
__global__ void k_convert(const float* __restrict__ x, u16* __restrict__ xb, int n4) {
  int i = blockIdx.x * blockDim.x + threadIdx.x;
  if (i >= n4) return;
  float4 v = ((const float4*)x)[i];
  ushort4 o;
  o.x = f2bf(v.x); o.y = f2bf(v.y); o.z = f2bf(v.z); o.w = f2bf(v.w);
  ((ushort4*)xb)[i] = o;
}

// ---------------- prep: W [k][n] fp32 -> Wt [n][k] bf16 ----------------
__global__ void k_transposeW(const float* __restrict__ W0, const float* __restrict__ W1,
                             const float* __restrict__ W2, const float* __restrict__ W3,
                             u16* __restrict__ Wt) {
  __shared__ float tile[64][65];
  const float* W = (blockIdx.z == 0) ? W0 : (blockIdx.z == 1) ? W1 : (blockIdx.z == 2) ? W2 : W3;
  u16* out = Wt + (size_t)blockIdx.z * (512 * 512);
  int k0 = blockIdx.x * 64, n0 = blockIdx.y * 64;
  int t = threadIdx.x;
#pragma unroll
  for (int i = 0; i < 16; ++i) {
    int idx = i * 256 + t;
    int r = idx >> 6, c = idx & 63;
    tile[r][c] = W[(size_t)(k0 + r) * 512 + n0 + c];
  }
  __syncthreads();
#pragma unroll
  for (int i = 0; i < 16; ++i) {
    int idx = i * 256 + t;
    int n = idx >> 6, k = idx & 63;
    out[(size_t)(n0 + n) * 512 + k0 + k] = f2bf(tile[k][n]);
  }
}

// ---------------- shared GEMM core: C[128][128] += A[m0:,k] * Bt[n0:,k]^T ----------------
// A: bf16 [M][512] row-major, Bt: bf16 [512 n][512 k] row-major. K=512, BK=64.
// LDS: A tile at [0,16K), B tile at [16K,32K), rows 128B, XOR-swizzled ((row&7)<<4).
__device__ __forceinline__ void gemm_core(const u16* __restrict__ A, const u16* __restrict__ Bt,
                                          int m0, int n0, uint8_t* lds, f32x4 (&acc)[4][4]) {
  int t = threadIdx.x;
  int lane = t & 63;
  int wid = t >> 6;
  int l15 = lane & 15, hib = (lane >> 4) * 16;
  int wm = wid >> 1, wn = wid & 1;
  const uint8_t* Ab = (const uint8_t*)A + (size_t)m0 * 1024;
  const uint8_t* Bb = (const uint8_t*)Bt + (size_t)n0 * 1024;
  for (int kk = 0; kk < 8; ++kk) {
    __syncthreads();
    int kof = kk * 128;
#pragma unroll
    for (int r = 0; r < 4; ++r) {
      int L = r * 4096 + t * 16;
      int row = L >> 7;
      int colU = (L & 127) ^ ((row & 7) << 4);  // inverse-swizzled source (rule 21)
      gll16(Ab + (size_t)row * 1024 + kof + colU, lds + L);
      gll16(Bb + (size_t)row * 1024 + kof + colU, lds + 16384 + L);
    }
    __syncthreads();
#pragma unroll
    for (int ks = 0; ks < 2; ++ks) {
      bf16x8 af[4], bfr[4];
#pragma unroll
      for (int mi = 0; mi < 4; ++mi) {
        int row = wm * 64 + mi * 16 + l15;
        af[mi] = *(const bf16x8*)(lds + row * 128 + ((ks * 64 + hib) ^ ((row & 7) << 4)));
      }
#pragma unroll
      for (int ni = 0; ni < 4; ++ni) {
        int row = wn * 64 + ni * 16 + l15;
        bfr[ni] = *(const bf16x8*)(lds + 16384 + row * 128 + ((ks * 64 + hib) ^ ((row & 7) << 4)));
      }
#pragma unroll
      for (int mi = 0; mi < 4; ++mi)
#pragma unroll
        for (int ni = 0; ni < 4; ++ni)
          acc[mi][ni] = __builtin_amdgcn_mfma_f32_16x16x32_bf16(af[mi], bfr[ni], acc[mi][ni], 0, 0, 0);
    }
  }
  __syncthreads();
}

// ---------------- QKV projection GEMM (z: 0=Q, 1=K, 2=V-transposed) ----------------
__global__ __launch_bounds__(256, 2) void k_gemm_qkv(
    const u16* __restrict__ A, const u16* __restrict__ Wt,
    const float* __restrict__ bq, const float* __restrict__ bk, const float* __restrict__ bv,
    u16* __restrict__ Qo, u16* __restrict__ Ko, u16* __restrict__ Vt) {
  __shared__ uint8_t lds[34816];
  int z = blockIdx.z;
  const u16* Bt = Wt + (size_t)z * (512 * 512);
  const float* bias = (z == 0) ? bq : (z == 1) ? bk : bv;
  int m0 = blockIdx.y * 128, n0 = blockIdx.x * 128;
  int t = threadIdx.x, lane = t & 63, wid = t >> 6;
  int l15 = lane & 15;
  int wm = wid >> 1, wn = wid & 1;

  f32x4 acc[4][4] = {};
  gemm_core(A, Bt, m0, n0, lds, acc);

  if (z != 2) {
    u16* out = (z == 0) ? Qo : Ko;
#pragma unroll
    for (int mi = 0; mi < 4; ++mi)
#pragma unroll
      for (int ni = 0; ni < 4; ++ni) {
        int c = wn * 64 + ni * 16 + l15;
        float bsv = bias[n0 + c];
        int rbase = wm * 64 + mi * 16 + (lane >> 4) * 4;
#pragma unroll
        for (int i = 0; i < 4; ++i)
          *(u16*)(lds + (rbase + i) * 256 + c * 2) = f2bf(acc[mi][ni][i] + bsv);
      }
    __syncthreads();
#pragma unroll
    for (int rr = 0; rr < 8; ++rr) {
      int L = rr * 4096 + t * 16;
      int row = L >> 8, col = L & 255;
      *(uint4*)((uint8_t*)out + (size_t)(m0 + row) * 1024 + n0 * 2 + col) = *(const uint4*)(lds + L);
    }
  } else {
    // V: write transposed Vt[b*512 + n][s], LDS stride 272B per n-row
#pragma unroll
    for (int mi = 0; mi < 4; ++mi)
#pragma unroll
      for (int ni = 0; ni < 4; ++ni) {
        int c = wn * 64 + ni * 16 + l15;
        float bsv = bias[n0 + c];
        int rbase = wm * 64 + mi * 16 + (lane >> 4) * 4;
#pragma unroll
        for (int i = 0; i < 4; ++i)
          *(u16*)(lds + c * 272 + (rbase + i) * 2) = f2bf(acc[mi][ni][i] + bsv);
      }
    __syncthreads();
    int b = m0 >> 12, s0 = m0 & 4095;
#pragma unroll
    for (int rr = 0; rr < 8; ++rr) {
      int L = rr * 4096 + t * 16;
      int cidx = L >> 8, rb = L & 255;
      *(uint4*)((uint8_t*)Vt + (size_t)(b * 512 + n0 + cidx) * 8192 + s0 * 2 + rb) =
          *(const uint4*)(lds + cidx * 272 + rb);
    }
  }
}

// ---------------- output projection GEMM (fp32 out) ----------------
__global__ __launch_bounds__(256, 2) void k_gemm_out(
    const u16* __restrict__ A, const u16* __restrict__ Bt,
    const float* __restrict__ bias, float* __restrict__ out) {
  __shared__ uint8_t lds[32768];
  int m0 = blockIdx.y * 128, n0 = blockIdx.x * 128;
  int t = threadIdx.x, lane = t & 63, wid = t >> 6;
  int l15 = lane & 15;
  int wm = wid >> 1, wn = wid & 1;

  f32x4 acc[4][4] = {};
  gemm_core(A, Bt, m0, n0, lds, acc);

#pragma unroll
  for (int mi = 0; mi < 4; ++mi)
#pragma unroll
    for (int ni = 0; ni < 4; ++ni) {
      int c = wn * 64 + ni * 16 + l15;
      float bsv = bias[n0 + c];
      int rbase = wm * 64 + mi * 16 + (lane >> 4) * 4;
#pragma unroll
      for (int i = 0; i < 4; ++i)
        out[(size_t)(m0 + rbase + i) * 512 + n0 + c] = acc[mi][ni][i] + bsv;
    }
}

// ---------------- flash attention ----------------
// Q,K: bf16 [8192][512]; Vt: bf16 [b*512+h*64+d][4096]; O: bf16 [8192][512].
// Block: 4 waves x 32 q-rows = 128 q rows; KV tile 64. grid (32, 16).
__global__ __launch_bounds__(256, 2) void k_attn(
    const u16* __restrict__ Q, const u16* __restrict__ K,
    const u16* __restrict__ Vt, u16* __restrict__ O) {
  __shared__ uint8_t lds[24576];
  int t = threadIdx.x, lane = t & 63, wid = t >> 6;
  int l15 = lane & 15, hib = (lane >> 4) * 16;
  int bh = blockIdx.y, b = bh >> 3, h = bh & 7;
  int q0 = blockIdx.x * 128 + wid * 32;

  const float SC = 0.18033688011112042f;  // log2(e) / sqrt(64)

  // Q fragments, held in registers for the whole kernel
  bf16x8 qf[2][2];
#pragma unroll
  for (int qs = 0; qs < 2; ++qs)
#pragma unroll
    for (int ks = 0; ks < 2; ++ks) {
      size_t idx = (size_t)(b * 4096 + q0 + qs * 16 + l15) * 512 + h * 64 + ks * 32 + (lane >> 4) * 8;
      qf[qs][ks] = *(const bf16x8*)(Q + idx);
    }

  f32x4 o[2][4] = {};
  f32x4 mst[2], lst[2];
#pragma unroll
  for (int qs = 0; qs < 2; ++qs)
#pragma unroll
    for (int i = 0; i < 4; ++i) { mst[qs][i] = -3.0e38f; lst[qs][i] = 0.0f; }

  const uint8_t* Kbase = (const uint8_t*)K + (size_t)(b * 4096) * 1024 + h * 128;
  const uint8_t* Vbase = (const uint8_t*)Vt + (size_t)(b * 512 + h * 64) * 8192;
  uint8_t* Klds = lds;                         // [64 kv][128B], swizzled
  uint8_t* Vlds = lds + 8192;                  // [64 d][128B kv], swizzled
  uint8_t* Plds = lds + 16384 + wid * 2048;    // per-wave [16 q][128B kv], swizzled

  for (int kt = 0; kt < 64; ++kt) {
    __syncthreads();
    int kv0 = kt * 64;
#pragma unroll
    for (int r = 0; r < 2; ++r) {
      int L = r * 4096 + t * 16;
      int row = L >> 7;
      int colU = (L & 127) ^ ((row & 7) << 4);
      gll16(Kbase + (size_t)(kv0 + row) * 1024 + colU, Klds + L);
      gll16(Vbase + (size_t)row * 8192 + (size_t)kv0 * 2 + colU, Vlds + L);
    }
    __syncthreads();

    // K / V fragments shared across both q-subtiles
    bf16x8 kf[4][2], vf[4][2];
#pragma unroll
    for (int cg = 0; cg < 4; ++cg)
#pragma unroll
      for (int ks = 0; ks < 2; ++ks) {
        int row = cg * 16 + l15;
        int off = (ks * 64 + hib) ^ ((row & 7) << 4);
        kf[cg][ks] = *(const bf16x8*)(Klds + row * 128 + off);
        vf[cg][ks] = *(const bf16x8*)(Vlds + row * 128 + off);
      }

#pragma unroll
    for (int qs = 0; qs < 2; ++qs) {
      f32x4 s[4] = {};
#pragma unroll
      for (int cg = 0; cg < 4; ++cg)
#pragma unroll
        for (int ks = 0; ks < 2; ++ks)
          s[cg] = __builtin_amdgcn_mfma_f32_16x16x32_bf16(qf[qs][ks], kf[cg][ks], s[cg], 0, 0, 0);

      // online softmax: per-lane rows are (lane>>4)*4 + i
      f32x4 tm;
#pragma unroll
      for (int i = 0; i < 4; ++i)
        tm[i] = fmaxf(fmaxf(s[0][i], s[1][i]), fmaxf(s[2][i], s[3][i]));
#pragma unroll
      for (int i = 0; i < 4; ++i) tm[i] = rmax16(tm[i]);
      f32x4 mnew, alpha;
#pragma unroll
      for (int i = 0; i < 4; ++i) {
        mnew[i] = fmaxf(mst[qs][i], tm[i] * SC);
        alpha[i] = exp2f(mst[qs][i] - mnew[i]);
        mst[qs][i] = mnew[i];
      }
      f32x4 psum = {};
#pragma unroll
      for (int cg = 0; cg < 4; ++cg) {
        int c2 = (cg * 16 + l15) * 2;
#pragma unroll
        for (int i = 0; i < 4; ++i) {
          float p = exp2f(fmaf(s[cg][i], SC, -mnew[i]));
          psum[i] += p;
          int qr = (lane >> 4) * 4 + i;
          *(u16*)(Plds + qr * 128 + (c2 ^ ((qr & 7) << 4))) = f2bf(p);
        }
      }
#pragma unroll
      for (int i = 0; i < 4; ++i) {
        psum[i] = rsum16(psum[i]);
        lst[qs][i] = lst[qs][i] * alpha[i] + psum[i];
      }
#pragma unroll
      for (int dg = 0; dg < 4; ++dg)
#pragma unroll
        for (int i = 0; i < 4; ++i) o[qs][dg][i] *= alpha[i];

      // PV: re-fragment P via LDS (same-wave write->read, compiler inserts lgkmcnt)
      bf16x8 pa[2];
#pragma unroll
      for (int ks = 0; ks < 2; ++ks)
        pa[ks] = *(const bf16x8*)(Plds + l15 * 128 + ((ks * 64 + hib) ^ ((l15 & 7) << 4)));
#pragma unroll
      for (int dg = 0; dg < 4; ++dg)
#pragma unroll
        for (int ks = 0; ks < 2; ++ks)
          o[qs][dg] = __builtin_amdgcn_mfma_f32_16x16x32_bf16(pa[ks], vf[dg][ks], o[qs][dg], 0, 0, 0);
    }
  }

  // normalize + store bf16
#pragma unroll
  for (int qs = 0; qs < 2; ++qs) {
    f32x4 inv;
#pragma unroll
    for (int i = 0; i < 4; ++i) inv[i] = 1.0f / lst[qs][i];
#pragma unroll
    for (int dg = 0; dg < 4; ++dg) {
      int c = h * 64 + dg * 16 + l15;
#pragma unroll
      for (int i = 0; i < 4; ++i) {
        size_t r = (size_t)(b * 4096 + q0 + qs * 16 + (lane >> 4) * 4 + i);
        O[r * 512 + c] = f2bf(o[qs][dg][i] * inv[i]);
      }
    }
  }
}

extern "C" void kernel_launch(void* const* d_in, const int* in_sizes, int n_in,
                              void* d_out, int out_size, void* d_ws, size_t ws_size,
                              hipStream_t stream) {
  const float* x  = (const float*)d_in[0];
  const float* Wq = (const float*)d_in[1];
  const float* bq = (const float*)d_in[2];
  const float* Wk = (const float*)d_in[3];
  const float* bk = (const float*)d_in[4];
  const float* Wv = (const float*)d_in[5];
  const float* bv = (const float*)d_in[6];
  const float* Wo = (const float*)d_in[7];
  const float* bo = (const float*)d_in[8];
  float* out = (float*)d_out;

  uint8_t* ws = (uint8_t*)d_ws;
  u16* xb  = (u16*)(ws);                  // 8 MB; reused as attn output buffer
  u16* Wt  = (u16*)(ws + 8388608);        // 2 MB
  u16* Qb  = (u16*)(ws + 10485760);       // 8 MB
  u16* Kb  = (u16*)(ws + 18874368);       // 8 MB
  u16* Vtb = (u16*)(ws + 27262976);       // 8 MB  (total 34 MB)
  u16* attn = xb;

  k_convert<<<4096, 256, 0, stream>>>(x, xb, 1048576);
  k_transposeW<<<dim3(8, 8, 4), 256, 0, stream>>>(Wq, Wk, Wv, Wo, Wt);
  k_gemm_qkv<<<dim3(4, 64, 3), 256, 0, stream>>>(xb, Wt, bq, bk, bv, Qb, Kb, Vtb);
  k_attn<<<dim3(32, 16), 256, 0, stream>>>(Qb, Kb, Vtb, attn);
  k_gemm_out<<<dim3(4, 64), 256, 0, stream>>>(attn, Wt + 3 * 262144, bo, out);
}

// Round 2
// 152.908 us; speedup vs baseline: 1.6069x; 1.6069x over previous
//
#include <hip/hip_runtime.h>
#include <stdint.h>

// CustomMultiHeadAttention: B=2, S=4096, E=512, H=8, Dh=64, fp32 in/out.
// bf16 MFMA pipeline. ws layout (34 MB):
//   [0,    8 MB)  xb  : x as bf16 [8192][512]  (reused as attn output)
//   [8,   10 MB)  Wt  : Wq,Wk,Wv,Wo transposed bf16 [4][512 n][512 k]
//   [10,  18 MB)  Qb  : bf16 [8192][512]
//   [18,  26 MB)  Kb  : bf16 [8192][512]
//   [26,  34 MB)  Vtb : bf16 [b*512 + h*64 + d][4096 s]  (V transposed)

typedef __bf16 bf16_t;
typedef bf16_t bf16x8 __attribute__((ext_vector_type(8)));
typedef float f32x4 __attribute__((ext_vector_type(4)));
typedef unsigned short u16;
typedef unsigned int u32;

__device__ __forceinline__ u16 f2bf(float f) {
  return __builtin_bit_cast(u16, (bf16_t)f);
}

// async global->LDS, 16B per lane; LDS dest must be uniform-base + lane*16
__device__ __forceinline__ void gll16(const void* g, void* l) {
  __builtin_amdgcn_global_load_lds((__attribute__((address_space(1))) void*)(void*)(g),
                                   (__attribute__((address_space(3))) void*)(l), 16, 0, 0);
}

__device__ __forceinline__ float fexp2(float x) {
  float r; asm("v_exp_f32 %0, %1" : "=v"(r) : "v"(x)); return r;
}
__device__ __forceinline__ u32 cvtpk(float lo, float hi) {
  u32 r; asm("v_cvt_pk_bf16_f32 %0, %1, %2" : "=v"(r) : "v"(lo), "v"(hi)); return r;
}

// ---------------- prep: fp32 -> bf16 convert ----------------
__global__ void k_convert(const float* __restrict__ x, u16* __restrict__ xb, int n4) {
  int i = blockIdx.x * blockDim.x + threadIdx.x;
  if (i >= n4) return;
  float4 v = ((const float4*)x)[i];
  ushort4 o;
  o.x = f2bf(v.x); o.y = f2bf(v.y); o.z = f2bf(v.z); o.w = f2bf(v.w);
  ((ushort4*)xb)[i] = o;
}

// ---------------- prep: W [k][n] fp32 -> Wt [n][k] bf16 ----------------
__global__ void k_transposeW(const float* __restrict__ W0, const float* __restrict__ W1,
                             const float* __restrict__ W2, const float* __restrict__ W3,
                             u16* __restrict__ Wt) {
  __shared__ float tile[64][65];
  const float* W = (blockIdx.z == 0) ? W0 : (blockIdx.z == 1) ? W1 : (blockIdx.z == 2) ? W2 : W3;
  u16* out = Wt + (size_t)blockIdx.z * (512 * 512);
  int k0 = blockIdx.x * 64, n0 = blockIdx.y * 64;
  int t = threadIdx.x;
#pragma unroll
  for (int i = 0; i < 16; ++i) {
    int idx = i * 256 + t;
    int r = idx >> 6, c = idx & 63;
    tile[r][c] = W[(size_t)(k0 + r) * 512 + n0 + c];
  }
  __syncthreads();
#pragma unroll
  for (int i = 0; i < 16; ++i) {
    int idx = i * 256 + t;
    int n = idx >> 6, k = idx & 63;
    out[(size_t)(n0 + n) * 512 + k0 + k] = f2bf(tile[k][n]);
  }
}

// ---------------- shared GEMM core: C[128][128] += A[m0:,k] * Bt[n0:,k]^T ----------------
__device__ __forceinline__ void gemm_core(const u16* __restrict__ A, const u16* __restrict__ Bt,
                                          int m0, int n0, uint8_t* lds, f32x4 (&acc)[4][4]) {
  int t = threadIdx.x;
  int lane = t & 63;
  int wid = t >> 6;
  int l15 = lane & 15, hib = (lane >> 4) * 16;
  int wm = wid >> 1, wn = wid & 1;
  const uint8_t* Ab = (const uint8_t*)A + (size_t)m0 * 1024;
  const uint8_t* Bb = (const uint8_t*)Bt + (size_t)n0 * 1024;
  for (int kk = 0; kk < 8; ++kk) {
    __syncthreads();
    int kof = kk * 128;
#pragma unroll
    for (int r = 0; r < 4; ++r) {
      int L = r * 4096 + t * 16;
      int row = L >> 7;
      int colU = (L & 127) ^ ((row & 7) << 4);
      gll16(Ab + (size_t)row * 1024 + kof + colU, lds + L);
      gll16(Bb + (size_t)row * 1024 + kof + colU, lds + 16384 + L);
    }
    __syncthreads();
#pragma unroll
    for (int ks = 0; ks < 2; ++ks) {
      bf16x8 af[4], bfr[4];
#pragma unroll
      for (int mi = 0; mi < 4; ++mi) {
        int row = wm * 64 + mi * 16 + l15;
        af[mi] = *(const bf16x8*)(lds + row * 128 + ((ks * 64 + hib) ^ ((row & 7) << 4)));
      }
#pragma unroll
      for (int ni = 0; ni < 4; ++ni) {
        int row = wn * 64 + ni * 16 + l15;
        bfr[ni] = *(const bf16x8*)(lds + 16384 + row * 128 + ((ks * 64 + hib) ^ ((row & 7) << 4)));
      }
#pragma unroll
      for (int mi = 0; mi < 4; ++mi)
#pragma unroll
        for (int ni = 0; ni < 4; ++ni)
          acc[mi][ni] = __builtin_amdgcn_mfma_f32_16x16x32_bf16(af[mi], bfr[ni], acc[mi][ni], 0, 0, 0);
    }
  }
  __syncthreads();
}

// ---------------- QKV projection GEMM (z: 0=Q, 1=K, 2=V-transposed) ----------------
__global__ __launch_bounds__(256, 2) void k_gemm_qkv(
    const u16* __restrict__ A, const u16* __restrict__ Wt,
    const float* __restrict__ bq, const float* __restrict__ bk, const float* __restrict__ bv,
    u16* __restrict__ Qo, u16* __restrict__ Ko, u16* __restrict__ Vt) {
  __shared__ uint8_t lds[34816];
  int z = blockIdx.z;
  const u16* Bt = Wt + (size_t)z * (512 * 512);
  const float* bias = (z == 0) ? bq : (z == 1) ? bk : bv;
  int m0 = blockIdx.y * 128, n0 = blockIdx.x * 128;
  int t = threadIdx.x, lane = t & 63, wid = t >> 6;
  int l15 = lane & 15;
  int wm = wid >> 1, wn = wid & 1;

  f32x4 acc[4][4] = {};
  gemm_core(A, Bt, m0, n0, lds, acc);

  if (z != 2) {
    u16* out = (z == 0) ? Qo : Ko;
#pragma unroll
    for (int mi = 0; mi < 4; ++mi)
#pragma unroll
      for (int ni = 0; ni < 4; ++ni) {
        int c = wn * 64 + ni * 16 + l15;
        float bsv = bias[n0 + c];
        int rbase = wm * 64 + mi * 16 + (lane >> 4) * 4;
#pragma unroll
        for (int i = 0; i < 4; ++i)
          *(u16*)(lds + (rbase + i) * 256 + c * 2) = f2bf(acc[mi][ni][i] + bsv);
      }
    __syncthreads();
#pragma unroll
    for (int rr = 0; rr < 8; ++rr) {
      int L = rr * 4096 + t * 16;
      int row = L >> 8, col = L & 255;
      *(uint4*)((uint8_t*)out + (size_t)(m0 + row) * 1024 + n0 * 2 + col) = *(const uint4*)(lds + L);
    }
  } else {
#pragma unroll
    for (int mi = 0; mi < 4; ++mi)
#pragma unroll
      for (int ni = 0; ni < 4; ++ni) {
        int c = wn * 64 + ni * 16 + l15;
        float bsv = bias[n0 + c];
        int rbase = wm * 64 + mi * 16 + (lane >> 4) * 4;
#pragma unroll
        for (int i = 0; i < 4; ++i)
          *(u16*)(lds + c * 272 + (rbase + i) * 2) = f2bf(acc[mi][ni][i] + bsv);
      }
    __syncthreads();
    int b = m0 >> 12, s0 = m0 & 4095;
#pragma unroll
    for (int rr = 0; rr < 8; ++rr) {
      int L = rr * 4096 + t * 16;
      int cidx = L >> 8, rb = L & 255;
      *(uint4*)((uint8_t*)Vt + (size_t)(b * 512 + n0 + cidx) * 8192 + s0 * 2 + rb) =
          *(const uint4*)(lds + cidx * 272 + rb);
    }
  }
}

// ---------------- output projection GEMM (fp32 out) ----------------
__global__ __launch_bounds__(256, 2) void k_gemm_out(
    const u16* __restrict__ A, const u16* __restrict__ Bt,
    const float* __restrict__ bias, float* __restrict__ out) {
  __shared__ uint8_t lds[32768];
  int m0 = blockIdx.y * 128, n0 = blockIdx.x * 128;
  int t = threadIdx.x, lane = t & 63, wid = t >> 6;
  int l15 = lane & 15;
  int wm = wid >> 1, wn = wid & 1;

  f32x4 acc[4][4] = {};
  gemm_core(A, Bt, m0, n0, lds, acc);

#pragma unroll
  for (int mi = 0; mi < 4; ++mi)
#pragma unroll
    for (int ni = 0; ni < 4; ++ni) {
      int c = wn * 64 + ni * 16 + l15;
      float bsv = bias[n0 + c];
      int rbase = wm * 64 + mi * 16 + (lane >> 4) * 4;
#pragma unroll
      for (int i = 0; i < 4; ++i)
        out[(size_t)(m0 + rbase + i) * 512 + n0 + c] = acc[mi][ni][i] + bsv;
    }
}

// ---------------- flash attention (swapped-operand, O^T in registers) ----------------
// Per wave: 32 q rows (2 sub-tiles of 16). Lane mapping: q = lane&15 everywhere.
// QK^T: s = mfma(A=K_frag, B=Q_frag) -> S[q=l15][kv in-lane].
// PV:   o = mfma(A=V_frag, B=P_frag) -> O^T[d][q=l15]; kv permuted by sigma so the
//       P B-frag is exactly the lane's own cvt_pk words (zero cross-lane traffic):
//       sigma(32ks+8hi+2p+b) = 32ks+16(p>>1)+4hi+2(p&1)+b.
// Double-buffered K/V staging with manual vmcnt/s_barrier 2-phase pipeline.
__global__ __launch_bounds__(256, 2) void k_attn(
    const u16* __restrict__ Q, const u16* __restrict__ K,
    const u16* __restrict__ Vt, u16* __restrict__ O) {
  __shared__ uint8_t lds[32768];
  int t = threadIdx.x, lane = t & 63, wid = t >> 6;
  int l15 = lane & 15, hi = lane >> 4;
  int bh = blockIdx.y, b = bh >> 3, h = bh & 7;
  int q0 = blockIdx.x * 128 + wid * 32;

  const float SC = 0.18033688011112042f;  // log2(e) / sqrt(64)

  const uint8_t* Kbase = (const uint8_t*)K + (size_t)(b * 4096) * 1024 + h * 128;
  const uint8_t* Vbase = (const uint8_t*)Vt + (size_t)(b * 512 + h * 64) * 8192;

  // Q fragments (B-operand): Q[q=l15 (+qs*16)][e = ks*32 + hi*8 + j]
  bf16x8 qf[2][2];
#pragma unroll
  for (int qs = 0; qs < 2; ++qs)
#pragma unroll
    for (int ks = 0; ks < 2; ++ks)
      qf[qs][ks] = *(const bf16x8*)(Q + (size_t)(b * 4096 + q0 + qs * 16 + l15) * 512 +
                                    h * 64 + ks * 32 + hi * 8);

  f32x4 o[2][4] = {};
  float mst[2] = {-3.0e38f, -3.0e38f};
  float lst[2] = {0.0f, 0.0f};

  auto STAGE = [&](int buf, int kt) {
    uint8_t* Kl = lds + buf * 16384;
    uint8_t* Vl = Kl + 8192;
    int kv0 = kt * 64;
#pragma unroll
    for (int r = 0; r < 2; ++r) {
      int L = r * 4096 + t * 16;
      int row = L >> 7;
      int colU = (L & 127) ^ ((row & 7) << 4);
      gll16(Kbase + (size_t)(kv0 + row) * 1024 + colU, Kl + L);
      gll16(Vbase + (size_t)row * 8192 + (size_t)kv0 * 2 + colU, Vl + L);
    }
  };

  STAGE(0, 0);
  asm volatile("s_waitcnt vmcnt(0)" ::: "memory");
  __builtin_amdgcn_s_barrier();

  int cur = 0;
  for (int kt = 0; kt < 64; ++kt) {
    if (kt + 1 < 64) STAGE(cur ^ 1, kt + 1);  // prefetch flies under this tile's compute

    const uint8_t* Kl = lds + cur * 16384;
    const uint8_t* Vl = Kl + 8192;

    // K fragments (A-operand), shared by both q sub-tiles
    bf16x8 kA[2][4];
#pragma unroll
    for (int ks = 0; ks < 2; ++ks)
#pragma unroll
      for (int cg = 0; cg < 4; ++cg) {
        int row = cg * 16 + l15;
        kA[ks][cg] = *(const bf16x8*)(Kl + row * 128 + ((ks * 64 + hi * 16) ^ ((row & 7) << 4)));
      }

    u32 w[2][8];
#pragma unroll
    for (int qs = 0; qs < 2; ++qs) {
      f32x4 s[4] = {};
      __builtin_amdgcn_s_setprio(1);
#pragma unroll
      for (int ks = 0; ks < 2; ++ks)
#pragma unroll
        for (int cg = 0; cg < 4; ++cg)
          s[cg] = __builtin_amdgcn_mfma_f32_16x16x32_bf16(kA[ks][cg], qf[qs][ks], s[cg], 0, 0, 0);
      __builtin_amdgcn_s_setprio(0);

      // in-lane row max (q = l15), then across hi groups
      f32x4 mx;
#pragma unroll
      for (int i = 0; i < 4; ++i)
        mx[i] = fmaxf(fmaxf(s[0][i], s[1][i]), fmaxf(s[2][i], s[3][i]));
      float tm = fmaxf(fmaxf(mx[0], mx[1]), fmaxf(mx[2], mx[3]));
      tm = fmaxf(tm, __shfl_xor(tm, 16));
      tm = fmaxf(tm, __shfl_xor(tm, 32));
      tm *= SC;

      if (!__all(tm <= mst[qs] + 8.0f)) {   // T13 defer-max
        float mn = fmaxf(mst[qs], tm);
        float al = fexp2(mst[qs] - mn);
        mst[qs] = mn;
        lst[qs] *= al;
#pragma unroll
        for (int dg = 0; dg < 4; ++dg)
#pragma unroll
          for (int i = 0; i < 4; ++i) o[qs][dg][i] *= al;
      }

      float p[16];
      f32x4 ps4 = {};
#pragma unroll
      for (int cg = 0; cg < 4; ++cg)
#pragma unroll
        for (int i = 0; i < 4; ++i) {
          float pv = fexp2(fmaf(s[cg][i], SC, -mst[qs]));
          p[cg * 4 + i] = pv;
          ps4[i] += pv;
        }
      float ps = (ps4[0] + ps4[1]) + (ps4[2] + ps4[3]);
      ps += __shfl_xor(ps, 16);
      ps += __shfl_xor(ps, 32);
      lst[qs] += ps;

#pragma unroll
      for (int k8 = 0; k8 < 8; ++k8)
        w[qs][k8] = cvtpk(p[2 * k8], p[2 * k8 + 1]);
    }

    bf16x8 pa[2][2];
#pragma unroll
    for (int qs = 0; qs < 2; ++qs)
#pragma unroll
      for (int ks = 0; ks < 2; ++ks) {
        uint4 u;
        u.x = w[qs][4 * ks + 0]; u.y = w[qs][4 * ks + 1];
        u.z = w[qs][4 * ks + 2]; u.w = w[qs][4 * ks + 3];
        pa[qs][ks] = __builtin_bit_cast(bf16x8, u);
      }

    // PV with sigma-permuted V A-frags (two b64 reads each)
#pragma unroll
    for (int dg = 0; dg < 4; ++dg) {
      int row = dg * 16 + l15;
      int sw = (row & 7) << 4;
#pragma unroll
      for (int ks = 0; ks < 2; ++ks) {
        uint2 a0 = *(const uint2*)(Vl + row * 128 + ((ks * 64 + hi * 8) ^ sw));
        uint2 a1 = *(const uint2*)(Vl + row * 128 + ((ks * 64 + 32 + hi * 8) ^ sw));
        uint4 vv; vv.x = a0.x; vv.y = a0.y; vv.z = a1.x; vv.w = a1.y;
        bf16x8 va = __builtin_bit_cast(bf16x8, vv);
        __builtin_amdgcn_s_setprio(1);
        o[0][dg] = __builtin_amdgcn_mfma_f32_16x16x32_bf16(va, pa[0][ks], o[0][dg], 0, 0, 0);
        o[1][dg] = __builtin_amdgcn_mfma_f32_16x16x32_bf16(va, pa[1][ks], o[1][dg], 0, 0, 0);
        __builtin_amdgcn_s_setprio(0);
      }
    }

    asm volatile("s_waitcnt vmcnt(0)" ::: "memory");  // next tile arrived
    __builtin_amdgcn_s_barrier();
    cur ^= 1;
  }

  // epilogue: lane holds O^T[d = dg*16 + hi*4 + i][q = l15]; store 8B per (qs,dg)
#pragma unroll
  for (int qs = 0; qs < 2; ++qs) {
    float inv = 1.0f / lst[qs];
#pragma unroll
    for (int dg = 0; dg < 4; ++dg) {
      ushort4 pk;
      pk.x = f2bf(o[qs][dg][0] * inv);
      pk.y = f2bf(o[qs][dg][1] * inv);
      pk.z = f2bf(o[qs][dg][2] * inv);
      pk.w = f2bf(o[qs][dg][3] * inv);
      *(uint2*)(O + (size_t)(b * 4096 + q0 + qs * 16 + l15) * 512 + h * 64 + dg * 16 + hi * 4) =
          __builtin_bit_cast(uint2, pk);
    }
  }
}

extern "C" void kernel_launch(void* const* d_in, const int* in_sizes, int n_in,
                              void* d_out, int out_size, void* d_ws, size_t ws_size,
                              hipStream_t stream) {
  const float* x  = (const float*)d_in[0];
  const float* Wq = (const float*)d_in[1];
  const float* bq = (const float*)d_in[2];
  const float* Wk = (const float*)d_in[3];
  const float* bk = (const float*)d_in[4];
  const float* Wv = (const float*)d_in[5];
  const float* bv = (const float*)d_in[6];
  const float* Wo = (const float*)d_in[7];
  const float* bo = (const float*)d_in[8];
  float* out = (float*)d_out;

  uint8_t* ws = (uint8_t*)d_ws;
  u16* xb  = (u16*)(ws);                  // 8 MB; reused as attn output buffer
  u16* Wt  = (u16*)(ws + 8388608);        // 2 MB
  u16* Qb  = (u16*)(ws + 10485760);       // 8 MB
  u16* Kb  = (u16*)(ws + 18874368);       // 8 MB
  u16* Vtb = (u16*)(ws + 27262976);       // 8 MB  (total 34 MB)
  u16* attn = xb;

  k_convert<<<4096, 256, 0, stream>>>(x, xb, 1048576);
  k_transposeW<<<dim3(8, 8, 4), 256, 0, stream>>>(Wq, Wk, Wv, Wo, Wt);
  k_gemm_qkv<<<dim3(4, 64, 3), 256, 0, stream>>>(xb, Wt, bq, bk, bv, Qb, Kb, Vtb);
  k_attn<<<dim3(32, 16), 256, 0, stream>>>(Qb, Kb, Vtb, attn);
  k_gemm_out<<<dim3(4, 64), 256, 0, stream>>>(attn, Wt + 3 * 262144, bo, out);
}